// Round 5
// baseline (311.506 us; speedup 1.0000x reference)
//
#include <hip/hip_runtime.h>

// ContinuousPool: 10x [cur += p*(maxpool3x3_same(cur)-cur)] then avgpool2x2.
// STREAMING SYSTOLIC CASCADE, zero-sync: each WAVE autonomously owns a 64-row
// half-plane (lane l holds cols 2l,2l+1). Raw rows stream through a 10-stage
// in-register pipeline; stage i keeps {h_{i-1}(R-2), h_{i-1}(R-1),
// S_{i-1}(R-1)} = 6 VGPRs and emits S_i(R-1) = lerp(S_{i-1}(R-1),
// max3(h(R-2),h(R-1),h(R))), h = horizontal DPP 3-max. Stage-10 rows feed the
// 2x2 avgpool and stream to global. NO barriers, NO LDS, NO cross-wave deps:
// prior rounds proved barrier/conflict changes are null (291/293/297 us for 3
// structures) -> limiter was the per-step rendezvous itself (VALUBusy ~30%).
// Vertical seam: 10 redundant halo rows per side (stream 84 rows for 64 core,
// +16% VALU). Padding rows use finite sentinel -1e37 (not -inf: lerp would
// NaN on inf-inf); sentinel propagates exactly, loses every max vs real data
// -> core outputs bit-identical to the -inf reference semantics.
// amdgpu_waves_per_eu(4,5): VGPR budget 102 >= ~95 live, so the allocator
// cannot repeat round-2's collapse-to-64-and-spill (spill tripwire:
// WRITE_SIZE >> 52 MB).

#define PW 128
#define NSTAGE 10
#define HALO 10
#define CORE 64
#define NITER 84        // CORE + 2*HALO rows streamed per wave
#define UNROLL 3        // h-window rotation period 3 -> zero v_mov renaming
#define SENT -1.0e37f

__device__ __forceinline__ float wshr1(float x) {
    // wave_shr:1 -> lane i gets lane i-1; lane 0 -> old(-inf) == padding
    int r = __builtin_amdgcn_update_dpp((int)0xff800000, __float_as_int(x),
                                        0x138, 0xf, 0xf, false);
    return __int_as_float(r);
}
__device__ __forceinline__ float wshl1(float x) {
    // wave_shl:1 -> lane i gets lane i+1; lane 63 -> old(-inf)
    int r = __builtin_amdgcn_update_dpp((int)0xff800000, __float_as_int(x),
                                        0x130, 0xf, 0xf, false);
    return __int_as_float(r);
}
__device__ __forceinline__ float max3f(float a, float b, float c) {
    return fmaxf(fmaxf(a, b), c);   // folds to v_max3_f32
}

__global__ __attribute__((amdgpu_flat_work_group_size(256, 256),
                          amdgpu_waves_per_eu(4, 5)))
void cpool_kernel(const float* __restrict__ x, const float* __restrict__ ps,
                  float* __restrict__ out) {
    const int wv    = threadIdx.x >> 6;       // wave in block: 0..3
    const int lane  = threadIdx.x & 63;       // cols 2*lane, 2*lane+1
    const int wg    = blockIdx.x * 4 + wv;    // global wave id: 0..6143
    const int plane = wg >> 1;                // (n,c) plane: 0..3071
    const int rbase = (wg & 1) * CORE;        // 0 (top half) or 64 (bottom)
    const float p = ps[plane % 96];

    const float2* __restrict__ xp = (const float2*)(x + (size_t)plane * (PW * PW));
    float* __restrict__ op = out + (size_t)plane * (64 * 64) + lane;

    // Per-stage pipeline state. H[k][i] = h of stage-i input rows, 3-slot
    // rotation (only 2 slots live across the backedge); S[i] = stage-i input
    // row value one behind. All static-indexed after unroll -> registers.
    float H[3][NSTAGE][2];
    float S[NSTAGE][2];
#pragma unroll
    for (int i = 0; i < NSTAGE; ++i) {
        S[i][0] = SENT; S[i][1] = SENT;
#pragma unroll
        for (int k = 0; k < 3; ++k) { H[k][i][0] = SENT; H[k][i][1] = SENT; }
    }

    const int t0 = rbase - HALO;              // first streamed row index
    float2 raw[UNROLL];                       // lookahead ring (3 rows)
#pragma unroll
    for (int k = 0; k < UNROLL; ++k) {
        int tr = t0 + k;
        raw[k] = ((unsigned)tr < (unsigned)PW) ? xp[tr * 64 + lane]
                                               : make_float2(SENT, SENT);
    }

    float pend = 0.0f;                        // avgpool row-pair accumulator

#pragma unroll 1
    for (int tb = 0; tb < NITER; tb += UNROLL) {
#pragma unroll
        for (int u = 0; u < UNROLL; ++u) {
            const int t = t0 + tb + u;        // row fed into stage 1 (uniform)
            float c0 = raw[u].x, c1 = raw[u].y;

            // refill ring with row t+UNROLL (uniform guard; OOB -> sentinel)
            {
                int tn = t + UNROLL;
                raw[u] = ((unsigned)tn < (unsigned)PW)
                             ? xp[tn * 64 + lane]
                             : make_float2(SENT, SENT);
            }

            // 10-stage cascade; c = S_{i-1}(R) entering stage i, R = t-(i-1)
#pragma unroll
            for (int i = 0; i < NSTAGE; ++i) {
                float L = wshr1(c1);
                float R = wshl1(c0);
                float hn0 = max3f(L, c0, c1);     // h_{i-1}(R) cols 2l-1..2l+1
                float hn1 = max3f(c0, c1, R);     //              2l..2l+2
                float o0 = fmaf(p, max3f(H[u % 3][i][0], H[(u + 1) % 3][i][0], hn0)
                                       - S[i][0], S[i][0]);
                float o1 = fmaf(p, max3f(H[u % 3][i][1], H[(u + 1) % 3][i][1], hn1)
                                       - S[i][1], S[i][1]);
                H[(u + 2) % 3][i][0] = hn0;
                H[(u + 2) % 3][i][1] = hn1;
                S[i][0] = c0; S[i][1] = c1;
                c0 = o0; c1 = o1;                 // S_i(R-1) -> next stage
            }

            // c = final (step-10) value of row rr
            const int rr = t - NSTAGE;
            if (rr >= rbase && rr < rbase + CORE) {   // uniform
                float hs = c0 + c1;                   // horizontal pair-sum
                if ((rr & 1) == 0) {
                    pend = hs;
                } else {
                    op[(rr >> 1) * 64] = 0.25f * (pend + hs);
                }
            }
        }
    }
}

extern "C" void kernel_launch(void* const* d_in, const int* in_sizes, int n_in,
                              void* d_out, int out_size, void* d_ws, size_t ws_size,
                              hipStream_t stream) {
    const float* x  = (const float*)d_in[0];   // (32,96,128,128) fp32
    const float* ps = (const float*)d_in[1];   // (1,96,1,1) fp32
    float* out = (float*)d_out;                // (32,96,64,64) fp32
    (void)in_sizes; (void)n_in; (void)out_size; (void)d_ws; (void)ws_size;

    // 3072 planes x 2 half-planes = 6144 waves = 1536 blocks of 256
    cpool_kernel<<<dim3(1536), dim3(256), 0, stream>>>(x, ps, out);
}